// Round 1
// baseline (1398.666 us; speedup 1.0000x reference)
//
#include <hip/hip_runtime.h>
#include <math.h>

#define B_TOT 1024
#define N_TOT 200
#define DIM 128
#define FDIM 384        // 3*DIM
#define NT 32           // n-rows per tile
#define THREADS 256
#define CTX_STRIDE 36   // padded row stride (36*4B = 144B = 9*16B, keeps b128 alignment)

__global__ __launch_bounds__(THREADS, 2)
void acv_kernel(const int* __restrict__ xs_xt,        // [B][N][2]
                const int* __restrict__ path_idx,     // [B][N]
                const float* __restrict__ value_vocab,// [100000][128]
                const float* __restrict__ path_vocab, // [500000][128]
                const float* __restrict__ W,          // [128][384] row-major (d, f)
                const float* __restrict__ att_vec,    // [128]
                const float* __restrict__ dense_w,    // [128][128] (d, o)
                const float* __restrict__ dense_b,    // [128]
                float* __restrict__ out)              // [B][128]
{
    __shared__ float ctxT[FDIM][CTX_STRIDE];  // ctx transposed: [f][n_local]
    __shared__ float P_w[4][DIM];             // per-wave unnormalized weighted-comb sums
    __shared__ float L_w[4];                  // per-wave exp sums
    __shared__ float av_s[DIM];
    __shared__ float code_s[DIM];

    const int b    = blockIdx.x;
    const int tid  = threadIdx.x;
    const int lane = tid & 63;
    const int wave = tid >> 6;
    const int d0   = (tid & 31) * 4;   // 4 output dims per thread
    const int ng   = tid >> 5;         // n-group 0..7 (uniform within 32-lane half-wave)
    const int n0   = ng * 4;           // 4 n-rows per thread

    // init shared state
    if (tid < DIM) {
        P_w[0][tid] = 0.f; P_w[1][tid] = 0.f; P_w[2][tid] = 0.f; P_w[3][tid] = 0.f;
        av_s[tid] = att_vec[tid];
    }
    if (tid < 4) L_w[tid] = 0.f;
    __syncthreads();

    const int* xs_b = xs_xt + (size_t)b * (N_TOT * 2);
    const int* p_b  = path_idx + (size_t)b * N_TOT;

    for (int t0 = 0; t0 < N_TOT; t0 += NT) {
        const int nt = (N_TOT - t0 < NT) ? (N_TOT - t0) : NT;

        // ---- stage ctx tile (gather embeddings), transposed into LDS ----
        for (int i = tid; i < nt * FDIM; i += THREADS) {
            int nl = i / FDIM;
            int f  = i - nl * FDIM;
            int n  = t0 + nl;
            float v;
            if (f < 128) {
                v = value_vocab[(size_t)xs_b[2 * n] * DIM + f];
            } else if (f < 256) {
                v = path_vocab[(size_t)p_b[n] * DIM + (f - 128)];
            } else {
                v = value_vocab[(size_t)xs_b[2 * n + 1] * DIM + (f - 256)];
            }
            ctxT[f][nl] = v;
        }
        __syncthreads();

        // ---- k-loop: acc[j][r] = sum_f ctx[n0+j][f] * W[d0+r][f] ----
        float acc[4][4];
        #pragma unroll
        for (int j = 0; j < 4; ++j)
            #pragma unroll
            for (int r = 0; r < 4; ++r) acc[j][r] = 0.f;

        for (int k4 = 0; k4 < FDIM; k4 += 4) {
            float wr[4][4];   // [r][kk]
            float ck[4][4];   // [kk][j]
            #pragma unroll
            for (int r = 0; r < 4; ++r) {
                float4 t = *(const float4*)&W[(d0 + r) * FDIM + k4];
                wr[r][0] = t.x; wr[r][1] = t.y; wr[r][2] = t.z; wr[r][3] = t.w;
            }
            #pragma unroll
            for (int kk = 0; kk < 4; ++kk) {
                float4 t = *(const float4*)&ctxT[k4 + kk][n0];
                ck[kk][0] = t.x; ck[kk][1] = t.y; ck[kk][2] = t.z; ck[kk][3] = t.w;
            }
            #pragma unroll
            for (int j = 0; j < 4; ++j)
                #pragma unroll
                for (int r = 0; r < 4; ++r)
                    #pragma unroll
                    for (int kk = 0; kk < 4; ++kk)
                        acc[j][r] = fmaf(ck[kk][j], wr[r][kk], acc[j][r]);
        }

        // ---- tanh, scores, exp-weighted accumulation (no max-sub: |s| <= 6.4) ----
        float av4[4] = { av_s[d0], av_s[d0 + 1], av_s[d0 + 2], av_s[d0 + 3] };
        float pc[4] = { 0.f, 0.f, 0.f, 0.f };
        float lsum = 0.f;
        #pragma unroll
        for (int j = 0; j < 4; ++j) {
            #pragma unroll
            for (int r = 0; r < 4; ++r) acc[j][r] = tanhf(acc[j][r]);
            float s = acc[j][0] * av4[0] + acc[j][1] * av4[1]
                    + acc[j][2] * av4[2] + acc[j][3] * av4[3];
            // butterfly sum over the 32 lanes sharing this n-set (covers all 128 d)
            #pragma unroll
            for (int off = 1; off < 32; off <<= 1) s += __shfl_xor(s, off, 64);
            bool valid = (t0 + n0 + j) < N_TOT;
            float ej = valid ? __expf(s) : 0.f;
            lsum += ej;
            #pragma unroll
            for (int r = 0; r < 4; ++r) pc[r] += ej * acc[j][r];
        }
        // combine the two half-waves (same d-set, different n-groups)
        #pragma unroll
        for (int r = 0; r < 4; ++r) pc[r] += __shfl_xor(pc[r], 32, 64);
        lsum += __shfl_xor(lsum, 32, 64);
        if (lane < 32) {
            #pragma unroll
            for (int r = 0; r < 4; ++r) P_w[wave][d0 + r] += pc[r];
            if (lane == 0) L_w[wave] += lsum;
        }
        __syncthreads();  // ctxT consumed; safe to restage next tile
    }

    // ---- finalize: code = P / L ----
    if (tid < DIM) {
        float Pd = P_w[0][tid] + P_w[1][tid] + P_w[2][tid] + P_w[3][tid];
        float Lt = L_w[0] + L_w[1] + L_w[2] + L_w[3];
        code_s[tid] = Pd / Lt;
    }
    __syncthreads();

    // ---- dense + sigmoid ----
    if (tid < DIM) {
        float a = dense_b[tid];
        #pragma unroll 4
        for (int d = 0; d < DIM; ++d) a = fmaf(code_s[d], dense_w[d * DIM + tid], a);
        out[(size_t)b * DIM + tid] = 1.f / (1.f + __expf(-a));
    }
}

extern "C" void kernel_launch(void* const* d_in, const int* in_sizes, int n_in,
                              void* d_out, int out_size, void* d_ws, size_t ws_size,
                              hipStream_t stream) {
    const int*   xs_xt       = (const int*)d_in[0];
    const int*   path_idx    = (const int*)d_in[1];
    const float* value_vocab = (const float*)d_in[2];
    const float* path_vocab  = (const float*)d_in[3];
    const float* W           = (const float*)d_in[4];
    const float* att_vec     = (const float*)d_in[5];
    const float* dense_w     = (const float*)d_in[6];
    const float* dense_b     = (const float*)d_in[7];
    float*       out         = (float*)d_out;

    acv_kernel<<<B_TOT, THREADS, 0, stream>>>(xs_xt, path_idx, value_vocab, path_vocab,
                                              W, att_vec, dense_w, dense_b, out);
}

// Round 2
// 205.800 us; speedup vs baseline: 6.7962x; 6.7962x over previous
//
#include <hip/hip_runtime.h>
#include <math.h>

#define DIM 128
#define N_TOT 200
#define TILE_N 16
#define NTILES 13          // ceil(200/16)
#define KSTEPS 12          // 384 / 32
#define THREADS 512        // 8 waves; wave w owns d-rows [16w, 16w+16)

typedef __attribute__((ext_vector_type(8))) short short8;
typedef __attribute__((ext_vector_type(4))) float f32x4;

__device__ __forceinline__ unsigned short f2bf(float f) {
    unsigned int u = __float_as_uint(f);
    u += 0x7fffu + ((u >> 16) & 1u);          // round-to-nearest-even
    return (unsigned short)(u >> 16);
}
__device__ __forceinline__ float fast_tanh(float x) {
    return 1.f - 2.f / (__expf(2.f * x) + 1.f);
}

__global__ __launch_bounds__(THREADS, 4)
void acv_kernel(const int* __restrict__ xs_xt,        // [B][N][2]
                const int* __restrict__ path_idx,     // [B][N]
                const float* __restrict__ value_vocab,// [100000][128]
                const float* __restrict__ path_vocab, // [500000][128]
                const float* __restrict__ W,          // [128][384] (d, f)
                const float* __restrict__ att_vec,    // [128]
                const float* __restrict__ dense_w,    // [128][128] (d, o)
                const float* __restrict__ dense_b,    // [128]
                float* __restrict__ out)              // [B][128]
{
    // ctx tile, bf16, XOR-swizzled, double-buffered: [n][384] row = 768 B
    __shared__ __align__(16) unsigned short ctx_lds[2][TILE_N * 384];
    __shared__ float spart[2][TILE_N][8];     // per-wave score partials
    __shared__ float code_s[DIM];
    __shared__ float red[4][DIM];

    const int b    = blockIdx.x;
    const int tid  = threadIdx.x;
    const int wave = tid >> 6;
    const int lane = tid & 63;
    const int c    = lane & 15;               // MFMA col / row-within-tile
    const int g    = lane >> 4;               // k-group / row-group

    const int* xs_b = xs_xt + b * (N_TOT * 2);
    const int* p_b  = path_idx + b * N_TOT;

    // ---- one-time: W fragments into registers (wave owns d = 16*wave + c) ----
    short8 wfrag[KSTEPS];
    {
        const float* wrow = W + (size_t)(16 * wave + c) * 384 + 8 * g;
        #pragma unroll
        for (int ks = 0; ks < KSTEPS; ++ks) {
            float4 q0 = *(const float4*)(wrow + 32 * ks);
            float4 q1 = *(const float4*)(wrow + 32 * ks + 4);
            short8 w;
            w[0] = (short)f2bf(q0.x); w[1] = (short)f2bf(q0.y);
            w[2] = (short)f2bf(q0.z); w[3] = (short)f2bf(q0.w);
            w[4] = (short)f2bf(q1.x); w[5] = (short)f2bf(q1.y);
            w[6] = (short)f2bf(q1.z); w[7] = (short)f2bf(q1.w);
            wfrag[ks] = w;
        }
    }
    const float a_val = att_vec[16 * wave + c];

    // ---- staging helpers (T14 split: load-early / write-late) ----
    // 16 n-rows * 384 f = 3072 float2 units; 6 per thread.
    auto stage_load = [&](int tile, float2* v, int* wa) {
        const int t0 = tile * TILE_N;
        #pragma unroll
        for (int it = 0; it < 6; ++it) {
            int j  = it * THREADS + tid;       // 0..3071
            int nl = j / 192;                  // local n row
            int f2 = j - nl * 192;             // float2 index in row
            int n  = t0 + nl;
            float2 t = make_float2(0.f, 0.f);
            if (n < N_TOT) {
                int f = f2 * 2;
                const float* src;
                if (f < 128)      src = value_vocab + (size_t)xs_b[2 * n]     * DIM + f;
                else if (f < 256) src = path_vocab  + (size_t)p_b[n]          * DIM + (f - 128);
                else              src = value_vocab + (size_t)xs_b[2 * n + 1] * DIM + (f - 256);
                t = *(const float2*)src;
            }
            v[it]  = t;
            wa[it] = (nl * 768 + f2 * 4) ^ ((nl & 7) << 4);   // swizzled byte addr
        }
    };
    auto stage_write = [&](int buf, const float2* v, const int* wa) {
        char* base = (char*)ctx_lds[buf];
        #pragma unroll
        for (int it = 0; it < 6; ++it) {
            unsigned int pk = ((unsigned int)f2bf(v[it].y) << 16) | (unsigned int)f2bf(v[it].x);
            *(unsigned int*)(base + wa[it]) = pk;
        }
    };

    float2 sv[6]; int swa[6];
    stage_load(0, sv, swa);
    stage_write(0, sv, swa);
    __syncthreads();

    const int abase0 = c * 768 + 16 * g;       // A-frag byte base in tile
    const int aswz   = (c & 7) << 4;

    float P = 0.f, lsum = 0.f;

    for (int t = 0; t < NTILES; ++t) {
        const int p = t & 1;
        if (t + 1 < NTILES) stage_load(t + 1, sv, swa);   // issue gathers early

        // ---- MFMA: comb-tile = ctx[16n x 384] * W[d-slice]^T ----
        f32x4 acc = {0.f, 0.f, 0.f, 0.f};
        const char* cb = (const char*)ctx_lds[p];
        #pragma unroll
        for (int ks = 0; ks < KSTEPS; ++ks) {
            short8 af = *(const short8*)(cb + ((abase0 + 64 * ks) ^ aswz));
            acc = __builtin_amdgcn_mfma_f32_16x16x32_bf16(af, wfrag[ks], acc, 0, 0, 0);
        }

        // ---- tanh + per-wave score partials (lane holds comb[n=4g+r][d=16w+c]) ----
        float comb[4], sp[4];
        #pragma unroll
        for (int r = 0; r < 4; ++r) {
            comb[r] = fast_tanh(acc[r]);
            sp[r]   = comb[r] * a_val;
        }
        #pragma unroll
        for (int r = 0; r < 4; ++r) {          // reduce over the 16 cols
            sp[r] += __shfl_xor(sp[r], 1, 64);
            sp[r] += __shfl_xor(sp[r], 2, 64);
            sp[r] += __shfl_xor(sp[r], 4, 64);
            sp[r] += __shfl_xor(sp[r], 8, 64);
        }
        if (c == 0) {
            #pragma unroll
            for (int r = 0; r < 4; ++r) spart[p][4 * g + r][wave] = sp[r];
        }

        if (t + 1 < NTILES) stage_write(p ^ 1, sv, swa);  // write-late (after compute)
        __syncthreads();

        // ---- combine 8 wave partials -> s[n]; exp-weighted accumulation ----
        #pragma unroll
        for (int r = 0; r < 4; ++r) {
            int n = 4 * g + r;
            const float4 s0 = *(const float4*)&spart[p][n][0];
            const float4 s1 = *(const float4*)&spart[p][n][4];
            float s = ((s0.x + s0.y) + (s0.z + s0.w)) + ((s1.x + s1.y) + (s1.z + s1.w));
            float e = (t * TILE_N + n < N_TOT) ? __expf(s) : 0.f;   // |s|<=~6: no max-sub
            lsum += e;
            P    += e * comb[r];
        }
    }

    // ---- finalize code[d] = P/L ----
    P    += __shfl_xor(P, 16, 64);
    P    += __shfl_xor(P, 32, 64);
    lsum += __shfl_xor(lsum, 16, 64);
    lsum += __shfl_xor(lsum, 32, 64);
    if (lane < 16) code_s[16 * wave + c] = P / lsum;
    __syncthreads();

    // ---- dense + sigmoid ----
    const int o   = tid & 127;
    const int seg = tid >> 7;
    float partial = 0.f;
    #pragma unroll 8
    for (int d = 32 * seg; d < 32 * seg + 32; ++d)
        partial = fmaf(code_s[d], dense_w[d * DIM + o], partial);
    red[seg][o] = partial;
    __syncthreads();
    if (tid < DIM) {
        float acc2 = dense_b[tid] + ((red[0][tid] + red[1][tid]) + (red[2][tid] + red[3][tid]));
        out[(size_t)b * DIM + tid] = 1.f / (1.f + __expf(-acc2));
    }
}

extern "C" void kernel_launch(void* const* d_in, const int* in_sizes, int n_in,
                              void* d_out, int out_size, void* d_ws, size_t ws_size,
                              hipStream_t stream) {
    const int*   xs_xt       = (const int*)d_in[0];
    const int*   path_idx    = (const int*)d_in[1];
    const float* value_vocab = (const float*)d_in[2];
    const float* path_vocab  = (const float*)d_in[3];
    const float* W           = (const float*)d_in[4];
    const float* att_vec     = (const float*)d_in[5];
    const float* dense_w     = (const float*)d_in[6];
    const float* dense_b     = (const float*)d_in[7];
    float*       out         = (float*)d_out;

    acv_kernel<<<1024, THREADS, 0, stream>>>(xs_xt, path_idx, value_vocab, path_vocab,
                                             W, att_vec, dense_w, dense_b, out);
}

// Round 3
// 137.615 us; speedup vs baseline: 10.1636x; 1.4955x over previous
//
#include <hip/hip_runtime.h>
#include <math.h>

#define DIM 128
#define N_TOT 200
#define HALF_ROWS 100
#define NTILES_H 7          // 7 tiles x 16 rows = 112 >= 100
#define KSTEPS 12           // 384 / 32
#define THREADS 512         // 8 waves: waves 0..6 compute one tile each

typedef __attribute__((ext_vector_type(8))) short short8;
typedef __attribute__((ext_vector_type(4))) float f32x4;

__device__ __forceinline__ unsigned short f2bf(float f) {
    unsigned int u = __float_as_uint(f);
    u += 0x7fffu + ((u >> 16) & 1u);          // RNE
    return (unsigned short)(u >> 16);
}
__device__ __forceinline__ float fast_tanh(float x) {
    return 1.f - 2.f / (__expf(2.f * x) + 1.f);
}

// d_ws layout: P[2048][128] float, then L[2048] float
__global__ __launch_bounds__(THREADS, 2)
void acv_phase1(const int* __restrict__ xs_xt,        // [B][N][2]
                const int* __restrict__ path_idx,     // [B][N]
                const float* __restrict__ value_vocab,
                const float* __restrict__ path_vocab,
                const float* __restrict__ W,          // [128][384]
                const float* __restrict__ att_vec,
                float* __restrict__ Pws,              // [2048][128]
                float* __restrict__ Lws)              // [2048]
{
    // W as bf16 B-fragments: frag(ds,ks): 64 lanes x 16B. 8*12*1024 = 96 KB
    __shared__ __align__(16) unsigned short wlds[8 * KSTEPS * 64 * 8];
    __shared__ float Pp[NTILES_H][DIM];
    __shared__ float Lp[NTILES_H];

    const int tid  = threadIdx.x;
    const int wave = tid >> 6;
    const int lane = tid & 63;
    const int c    = lane & 15;
    const int g    = lane >> 4;
    const int unit = blockIdx.x;          // (b, half)
    const int b    = unit >> 1;
    const int h    = unit & 1;

    // ---- stage W -> bf16 fragments in LDS (once per block) ----
    {
        const int d  = tid >> 2;          // 0..127
        const int q  = tid & 3;           // quarter of the row
        const int ds = d >> 4, cc = d & 15;
        const float* wrow = W + d * 384 + 96 * q;
        #pragma unroll
        for (int f8 = 0; f8 < 12; ++f8) {
            int f = 96 * q + 8 * f8;
            float4 a0 = *(const float4*)(wrow + 8 * f8);
            float4 a1 = *(const float4*)(wrow + 8 * f8 + 4);
            int ks = f >> 5, gg = (f >> 3) & 3;
            short8 wv;
            wv[0] = (short)f2bf(a0.x); wv[1] = (short)f2bf(a0.y);
            wv[2] = (short)f2bf(a0.z); wv[3] = (short)f2bf(a0.w);
            wv[4] = (short)f2bf(a1.x); wv[5] = (short)f2bf(a1.y);
            wv[6] = (short)f2bf(a1.z); wv[7] = (short)f2bf(a1.w);
            *(short8*)&wlds[(((ds * KSTEPS + ks) * 64) + (gg << 4) + cc) * 8] = wv;
        }
    }

    float av_reg[8];
    #pragma unroll
    for (int ds = 0; ds < 8; ++ds) av_reg[ds] = att_vec[16 * ds + c];

    __syncthreads();   // wlds ready

    if (wave < NTILES_H) {
        // ---- per-wave: gather ctx rows straight into A-fragments ----
        const int nloc_g = 16 * wave + c;                       // my gather row
        const int n_cl   = nloc_g < HALF_ROWS ? nloc_g : HALF_ROWS - 1;
        const int n_g    = h * HALF_ROWS + n_cl;
        const int* xs_b  = xs_xt + b * (N_TOT * 2);
        const int* p_b   = path_idx + b * N_TOT;

        const float* seg0 = value_vocab + (size_t)xs_b[2 * n_g]     * DIM + 8 * g;
        const float* seg1 = path_vocab  + (size_t)p_b[n_g]          * DIM + 8 * g;
        const float* seg2 = value_vocab + (size_t)xs_b[2 * n_g + 1] * DIM + 8 * g;
        const float* segp[3] = { seg0, seg1, seg2 };

        f32x4 acc[8];
        #pragma unroll
        for (int ds = 0; ds < 8; ++ds) acc[ds] = (f32x4){0.f, 0.f, 0.f, 0.f};

        float4 pf[4][2];
        #pragma unroll
        for (int k = 0; k < 4; ++k) {                 // prologue: 4 ksteps in flight
            const float* p = segp[0] + 32 * k;
            pf[k][0] = *(const float4*)p;
            pf[k][1] = *(const float4*)(p + 4);
        }

        #pragma unroll
        for (int ks = 0; ks < KSTEPS; ++ks) {
            short8 a;
            {
                float4 x0 = pf[ks & 3][0], x1 = pf[ks & 3][1];
                a[0] = (short)f2bf(x0.x); a[1] = (short)f2bf(x0.y);
                a[2] = (short)f2bf(x0.z); a[3] = (short)f2bf(x0.w);
                a[4] = (short)f2bf(x1.x); a[5] = (short)f2bf(x1.y);
                a[6] = (short)f2bf(x1.z); a[7] = (short)f2bf(x1.w);
            }
            if (ks + 4 < KSTEPS) {                    // keep 4 ksteps in flight
                const float* p = segp[(ks + 4) >> 2] + 32 * ((ks + 4) & 3);
                pf[ks & 3][0] = *(const float4*)p;
                pf[ks & 3][1] = *(const float4*)(p + 4);
            }
            #pragma unroll
            for (int ds = 0; ds < 8; ++ds) {
                short8 bf = *(const short8*)&wlds[((ds * KSTEPS + ks) * 64 + lane) * 8];
                acc[ds] = __builtin_amdgcn_mfma_f32_16x16x32_bf16(a, bf, acc[ds], 0, 0, 0);
            }
        }

        // ---- tanh + scores (lane holds comb[n=16w+4g+r][d=16ds+c]) ----
        float combv[8][4];
        float sp[4] = {0.f, 0.f, 0.f, 0.f};
        #pragma unroll
        for (int ds = 0; ds < 8; ++ds)
            #pragma unroll
            for (int r = 0; r < 4; ++r) {
                float t = fast_tanh(acc[ds][r]);
                combv[ds][r] = t;
                sp[r] = fmaf(t, av_reg[ds], sp[r]);
            }
        #pragma unroll
        for (int r = 0; r < 4; ++r) {                 // reduce over the 16 cols (c)
            sp[r] += __shfl_xor(sp[r], 1, 64);
            sp[r] += __shfl_xor(sp[r], 2, 64);
            sp[r] += __shfl_xor(sp[r], 4, 64);
            sp[r] += __shfl_xor(sp[r], 8, 64);
        }

        float Pl[8] = {0.f,0.f,0.f,0.f,0.f,0.f,0.f,0.f};
        float Ll = 0.f;
        #pragma unroll
        for (int r = 0; r < 4; ++r) {
            int nl = 16 * wave + 4 * g + r;
            float e = (nl < HALF_ROWS) ? __expf(sp[r]) : 0.f;   // |s|<=~5: no max-sub
            Ll += e;
            #pragma unroll
            for (int ds = 0; ds < 8; ++ds) Pl[ds] = fmaf(e, combv[ds][r], Pl[ds]);
        }
        #pragma unroll
        for (int ds = 0; ds < 8; ++ds) {              // reduce over g (4 row-groups)
            Pl[ds] += __shfl_xor(Pl[ds], 16, 64);
            Pl[ds] += __shfl_xor(Pl[ds], 32, 64);
        }
        Ll += __shfl_xor(Ll, 16, 64);
        Ll += __shfl_xor(Ll, 32, 64);
        if (g == 0) {
            #pragma unroll
            for (int ds = 0; ds < 8; ++ds) Pp[wave][16 * ds + c] = Pl[ds];
            if (c == 0) Lp[wave] = Ll;
        }
    }
    __syncthreads();

    // ---- block reduce over the 7 tiles; write half-partials to workspace ----
    if (tid < DIM) {
        float P = 0.f;
        #pragma unroll
        for (int t = 0; t < NTILES_H; ++t) P += Pp[t][tid];
        Pws[(size_t)unit * DIM + tid] = P;
    }
    if (tid == 128) {
        float L = 0.f;
        #pragma unroll
        for (int t = 0; t < NTILES_H; ++t) L += Lp[t];
        Lws[unit] = L;
    }
}

__global__ __launch_bounds__(128, 8)
void acv_phase2(const float* __restrict__ Pws, const float* __restrict__ Lws,
                const float* __restrict__ dense_w, const float* __restrict__ dense_b,
                float* __restrict__ out)
{
    __shared__ float code_s[DIM];
    const int b = blockIdx.x, tid = threadIdx.x;
    float L = Lws[2 * b] + Lws[2 * b + 1];
    code_s[tid] = (Pws[(size_t)(2 * b) * DIM + tid] + Pws[(size_t)(2 * b + 1) * DIM + tid]) / L;
    __syncthreads();
    float a = dense_b[tid];
    #pragma unroll 8
    for (int d = 0; d < DIM; ++d) a = fmaf(code_s[d], dense_w[d * DIM + tid], a);
    out[(size_t)b * DIM + tid] = 1.f / (1.f + __expf(-a));
}

extern "C" void kernel_launch(void* const* d_in, const int* in_sizes, int n_in,
                              void* d_out, int out_size, void* d_ws, size_t ws_size,
                              hipStream_t stream) {
    const int*   xs_xt       = (const int*)d_in[0];
    const int*   path_idx    = (const int*)d_in[1];
    const float* value_vocab = (const float*)d_in[2];
    const float* path_vocab  = (const float*)d_in[3];
    const float* W           = (const float*)d_in[4];
    const float* att_vec     = (const float*)d_in[5];
    const float* dense_w     = (const float*)d_in[6];
    const float* dense_b     = (const float*)d_in[7];
    float*       out         = (float*)d_out;

    float* Pws = (float*)d_ws;                 // 2048*128 floats
    float* Lws = Pws + 2048 * 128;             // 2048 floats

    acv_phase1<<<2048, THREADS, 0, stream>>>(xs_xt, path_idx, value_vocab, path_vocab,
                                             W, att_vec, Pws, Lws);
    acv_phase2<<<1024, 128, 0, stream>>>(Pws, Lws, dense_w, dense_b, out);
}